// Round 9
// baseline (2703.103 us; speedup 1.0000x reference)
//
#include <hip/hip_runtime.h>
#include <hip/hip_bf16.h>
#include <hip/hip_cooperative_groups.h>
#include <math.h>

namespace cg = cooperative_groups;

#define BB 8
#define LL 128
#define SS 384        // 3*L
#define BT 3072       // B*S
#define EE 256
#define DM 256
#define DI 512
#define DSTATE 16
#define RK 16
#define NL 4

typedef unsigned short u16;
typedef __attribute__((ext_vector_type(8))) short short8;
typedef __attribute__((ext_vector_type(4))) float f32x4;

__device__ __forceinline__ float bf(const u16 v){
    union { unsigned u; float f; } c; c.u = ((unsigned)v) << 16; return c.f;
}
__device__ __forceinline__ u16 f2bf(float f){
    union { float f; unsigned u; } c; c.f = f;
    unsigned x = c.u;
    unsigned r = (x >> 16) & 1u;
    x += 0x7fffu + r;
    return (u16)(x >> 16);
}
__device__ __forceinline__ unsigned pack2(float a, float b){
    return ((unsigned)f2bf(a)) | (((unsigned)f2bf(b)) << 16);
}
__device__ __forceinline__ int get_flag(const unsigned* nwraw){
    return (nwraw[0] == 0x3F800000u) ? 0 : 1;   // 1 = bf16 inputs
}

#define SWZ_NB 848     // 217088 frags / 256
#define CNV_NB 64

__device__ __constant__ int g_soff[13] = {0, 0, 262144, 524288, 786432,
                                          0, 131072, 262144, 393216,
                                          0, 24576, 49152, 73728};

struct SwzDesc { const void* src; u16* dst; int K; int N; int frags; };
struct PrepArgs {
    const void* csrc[23]; int cn[23]; int coff[23];
    SwzDesc sd[13];
};

// ---------------------------------------------------------------------------
// Params for the cooperative mega-kernel
// ---------------------------------------------------------------------------
struct Params {
    PrepArgs pa;
    const int* tsteps;
    const unsigned* nwraw;
    float* fin;
    // fp32 converted tensors
    const float *states, *actions, *goal, *te_W, *se_W, *se_b, *ge_W, *ge_b,
                *ae_W, *ae_b, *bb_b, *norm_w, *conv_w, *conv_b, *dt_W, *dt_b,
                *A_log, *Dp, *fnorm_w, *ps_W, *ps_b, *pa_W, *pa_b;
    // swizzled bf16 weights
    const u16 *bb_sw, *in_sw, *out_sw, *xp_sw;
    // activations
    float *residual, *xc_raw, *sz, *xc, *dtbuf, *ybuf, *dtBC;
    void* out;
};

#define CT 32
#define NCH (SS/CT)   // 12

// ---------------------------------------------------------------------------
// MEGA KERNEL: whole network in one cooperative launch.
// grid 512 x 256. Static LDS 55424 B -> exactly 2 blocks/CU.
// ---------------------------------------------------------------------------
__global__ __launch_bounds__(256, 2) void k_mega(Params P){
    cg::grid_group grid = cg::this_grid();
    __shared__ __align__(16) char smem[55424];
    const int tid = threadIdx.x;
    const int f = get_flag(P.nwraw);

    // ---------------- P0: prep (swizzle + convert) ----------------
    for (int vb = blockIdx.x; vb < SWZ_NB + CNV_NB; vb += gridDim.x){
        if (vb < SWZ_NB){
            int gid = vb*256 + tid;
            #pragma unroll 1
            for (int s = 0; s < 13; ++s){
                int fr = P.pa.sd[s].frags;
                if (gid < fr){
                    const int N = P.pa.sd[s].N;
                    const int l = gid & 63;
                    const int rest = gid >> 6;
                    const int kcn = P.pa.sd[s].K >> 5;
                    const int kc = rest % kcn;
                    const int nt = rest / kcn;
                    const int n  = nt*16 + (l & 15);
                    const int k0 = kc*32 + (l >> 4)*8;
                    u16 tmp[8];
                    if (f){
                        const u16* src = (const u16*)P.pa.sd[s].src;
                        #pragma unroll
                        for (int j = 0; j < 8; ++j) tmp[j] = src[(size_t)(k0+j)*N + n];
                    } else {
                        const float* src = (const float*)((const char*)P.pa.sd[s].src
                                                          + (size_t)g_soff[s]*2);
                        #pragma unroll
                        for (int j = 0; j < 8; ++j) tmp[j] = f2bf(src[(size_t)(k0+j)*N + n]);
                    }
                    *(short8*)(P.pa.sd[s].dst + (size_t)gid*8) = *(short8*)tmp;
                    break;
                }
                gid -= fr;
            }
        } else {
            const int stride = CNV_NB * 256;
            const int tid0 = (vb - SWZ_NB)*256 + tid;
            #pragma unroll 1
            for (int s = 0; s < 23; ++s){
                const int n = P.pa.cn[s];
                float* d = P.fin + P.pa.coff[s];
                if (f){
                    const u16* p = (const u16*)P.pa.csrc[s];
                    for (int i = tid0; i < n; i += stride) d[i] = bf(p[i]);
                } else {
                    const float* p = (const float*)P.pa.csrc[s];
                    for (int i = tid0; i < n; i += stride) d[i] = p[i];
                }
            }
        }
    }
    __threadfence(); grid.sync();

    // ---------------- P1: embed + bb_in GEMM ----------------
    for (int vb = blockIdx.x; vb < 192; vb += gridDim.x){
        const int bx = vb >> 1, by = vb & 1;
        __syncthreads();
        u16* sA = (u16*)smem;
        {
            const int m = tid >> 3, p = tid & 7, e0 = p*32;
            const int token = bx*32 + m;
            const int b = token / SS, t = token % SS;
            const int slot = t % 3, step = t / 3;
            const int ts = P.tsteps[b*LL + step];
            float v[32];
            const float* tp = P.te_W + ts*EE + e0;
            #pragma unroll
            for (int i = 0; i < 8; ++i) *(float4*)(&v[i*4]) = *(const float4*)(tp + i*4);
            const float *bias, *Wp, *g; int nk;
            if (slot == 0){ bias = P.ge_b; Wp = P.ge_W; g = P.goal    + (b*LL+step)*6; nk = 6; }
            else if (slot == 1){ bias = P.se_b; Wp = P.se_W; g = P.states + (b*LL+step)*6; nk = 6; }
            else { bias = P.ae_b; Wp = P.ae_W; g = P.actions + (b*LL+step)*3; nk = 3; }
            #pragma unroll
            for (int i = 0; i < 8; ++i){
                float4 bv = *(const float4*)(bias + e0 + i*4);
                v[i*4]+=bv.x; v[i*4+1]+=bv.y; v[i*4+2]+=bv.z; v[i*4+3]+=bv.w;
            }
            for (int k = 0; k < nk; ++k){
                float gv = g[k];
                const float* wr = Wp + k*EE + e0;
                #pragma unroll
                for (int i = 0; i < 8; ++i){
                    float4 wv = *(const float4*)(wr + i*4);
                    v[i*4]+=gv*wv.x; v[i*4+1]+=gv*wv.y; v[i*4+2]+=gv*wv.z; v[i*4+3]+=gv*wv.w;
                }
            }
            unsigned* dp = (unsigned*)sA + (m*264 + e0)/2;
            #pragma unroll
            for (int i = 0; i < 16; ++i) dp[i] = pack2(v[2*i], v[2*i+1]);
        }
        __syncthreads();
        const int w = tid >> 6, l = tid & 63;
        const int mt = w >> 1, nq = w & 1;
        f32x4 acc[4] = {{0,0,0,0},{0,0,0,0},{0,0,0,0},{0,0,0,0}};
        const u16* ap0 = sA + (mt*16 + (l&15))*264 + (l>>4)*8;
        #pragma unroll
        for (int kc = 0; kc < 8; ++kc){
            short8 a = *(const short8*)(ap0 + kc*32);
            #pragma unroll
            for (int nt = 0; nt < 4; ++nt){
                int ntg = by*8 + nq*4 + nt;
                short8 b8 = *(const short8*)(P.bb_sw + ((size_t)(ntg*8 + kc)*64 + l)*8);
                acc[nt] = __builtin_amdgcn_mfma_f32_16x16x32_bf16(a, b8, acc[nt], 0,0,0);
            }
        }
        const int mrow0 = bx*32 + mt*16 + (l>>4)*4;
        #pragma unroll
        for (int nt = 0; nt < 4; ++nt){
            int col = (by*8 + nq*4 + nt)*16 + (l&15);
            float bb = P.bb_b[col];
            #pragma unroll
            for (int r = 0; r < 4; ++r)
                P.residual[(mrow0+r)*DM + col] = acc[nt][r] + bb;
        }
    }
    __threadfence(); grid.sync();

    // ---------------- layers ----------------
    for (int lyr = 0; lyr < NL; ++lyr){
        const float* nwv   = P.norm_w + lyr*DM;
        const u16*  insw   = P.in_sw  + lyr*262144;
        const u16*  outsw  = P.out_sw + lyr*131072;
        const u16*  xpsw   = P.xp_sw  + lyr*24576;
        const float* cw    = P.conv_w + lyr*DI*4;
        const float* cb_   = P.conv_b + lyr*DI;
        const float* dtW   = P.dt_W   + lyr*RK*DI;
        const float* dtb   = P.dt_b   + lyr*DI;
        const float* Alog  = P.A_log  + lyr*DI*DSTATE;
        const float* Dpp   = P.Dp     + lyr*DI;

        // ---- inproj: RMSNorm + in_proj GEMM (768 vtiles) ----
        for (int vb = blockIdx.x; vb < 768; vb += gridDim.x){
            const int bx = vb >> 3, by = vb & 7;
            __syncthreads();
            u16* sA = (u16*)smem;
            {
                const int m = tid >> 3, p = tid & 7, e0 = p*32;
                const int row = bx*32 + m;
                float v[32];
                const float* rp = P.residual + row*DM + e0;
                #pragma unroll
                for (int i = 0; i < 8; ++i) *(float4*)(&v[i*4]) = *(const float4*)(rp + i*4);
                float s = 0.f;
                #pragma unroll
                for (int i = 0; i < 32; ++i) s += v[i]*v[i];
                s += __shfl_xor(s,1,64); s += __shfl_xor(s,2,64); s += __shfl_xor(s,4,64);
                const float scale = rsqrtf(s*(1.f/DM) + 1e-5f);
                const float* nwp = nwv + e0;
                unsigned* dp = (unsigned*)sA + (m*264 + e0)/2;
                #pragma unroll
                for (int i = 0; i < 16; ++i)
                    dp[i] = pack2(v[2*i]*scale*nwp[2*i], v[2*i+1]*scale*nwp[2*i+1]);
            }
            __syncthreads();
            const int w = tid >> 6, l = tid & 63;
            const int mt = w >> 1, nq = w & 1;
            f32x4 acc[4] = {{0,0,0,0},{0,0,0,0},{0,0,0,0},{0,0,0,0}};
            const u16* ap0 = sA + (mt*16 + (l&15))*264 + (l>>4)*8;
            #pragma unroll
            for (int kc = 0; kc < 8; ++kc){
                short8 a = *(const short8*)(ap0 + kc*32);
                #pragma unroll
                for (int nt = 0; nt < 4; ++nt){
                    int ntg = by*8 + nq*4 + nt;
                    short8 b8 = *(const short8*)(insw + ((size_t)(ntg*8 + kc)*64 + l)*8);
                    acc[nt] = __builtin_amdgcn_mfma_f32_16x16x32_bf16(a, b8, acc[nt], 0,0,0);
                }
            }
            const int mrow0 = bx*32 + mt*16 + (l>>4)*4;
            if (by < 4){
                #pragma unroll
                for (int nt = 0; nt < 4; ++nt){
                    int col = (by*8 + nq*4 + nt)*16 + (l&15);
                    #pragma unroll
                    for (int r = 0; r < 4; ++r)
                        P.xc_raw[(mrow0+r)*DI + col] = acc[nt][r];
                }
            } else {
                #pragma unroll
                for (int nt = 0; nt < 4; ++nt){
                    int col = (by*8 + nq*4 + nt)*16 + (l&15) - DI;
                    #pragma unroll
                    for (int r = 0; r < 4; ++r){
                        float z = acc[nt][r];
                        P.sz[(mrow0+r)*DI + col] = z / (1.f + __expf(-z));
                    }
                }
            }
        }
        __threadfence(); grid.sync();

        // ---- conv + xproj MFMA + dt (192 vtiles) ----
        for (int vb = blockIdx.x; vb < 192; vb += gridDim.x){
            __syncthreads();
            u16* sxc = (u16*)smem;
            float* sdtbc = (float*)(smem + 16640);
            const int base = vb * 16;
            const int t0 = base % SS;
            #pragma unroll
            for (int half = 0; half < 2; ++half){
                const int d = tid + half*256;
                const float w0 = cw[d*4+0], w1 = cw[d*4+1];
                const float w2 = cw[d*4+2], w3 = cw[d*4+3];
                const float cbv = cb_[d];
                const float* rp = P.xc_raw + (size_t)base*DI + d;
                float xm3=0.f, xm2=0.f, xm1=0.f;
                if (t0 > 0){
                    xm3 = rp[-3*DI]; xm2 = rp[-2*DI]; xm1 = rp[-DI];
                }
                #pragma unroll
                for (int tk = 0; tk < 16; ++tk){
                    float x0 = rp[tk*DI];
                    float a = cbv + w0*xm3 + w1*xm2 + w2*xm1 + w3*x0;
                    float s = a / (1.f + __expf(-a));
                    P.xc[(size_t)(base+tk)*DI + d] = s;
                    sxc[tk*520 + d] = f2bf(s);
                    xm3 = xm2; xm2 = xm1; xm1 = x0;
                }
            }
            __syncthreads();
            const int w = tid >> 6, l = tid & 63;
            if (w < 3){
                f32x4 acc = {0,0,0,0};
                const u16* ap0 = sxc + (l&15)*520 + (l>>4)*8;
                #pragma unroll
                for (int kc = 0; kc < 16; ++kc){
                    short8 a = *(const short8*)(ap0 + kc*32);
                    short8 b8 = *(const short8*)(xpsw + ((size_t)(w*16 + kc)*64 + l)*8);
                    acc = __builtin_amdgcn_mfma_f32_16x16x32_bf16(a, b8, acc, 0,0,0);
                }
                #pragma unroll
                for (int r = 0; r < 4; ++r)
                    sdtbc[((l>>4)*4 + r)*64 + w*16 + (l&15)] = acc[r];
            }
            __syncthreads();
            #pragma unroll
            for (int r = 0; r < 2; ++r){
                int i = tid + r*256;
                int t = i >> 5, j = i & 31;
                P.dtBC[(size_t)(base+t)*48 + 16 + j] = sdtbc[t*64 + 16 + j];
            }
            #pragma unroll
            for (int half = 0; half < 2; ++half){
                const int d = tid + half*256;
                const float db = dtb[d];
                float wr[16];
                #pragma unroll
                for (int r = 0; r < 16; ++r) wr[r] = dtW[r*DI + d];
                #pragma unroll
                for (int tk = 0; tk < 16; ++tk){
                    float a = db;
                    #pragma unroll
                    for (int r = 0; r < 16; ++r) a += sdtbc[tk*64 + r] * wr[r];
                    float sp = (a > 15.f) ? a : __logf(1.f + __expf(a));
                    P.dtbuf[(size_t)(base+tk)*DI + d] = sp;
                }
            }
        }
        __threadfence(); grid.sync();

        // ---- scan (blocks 0..255) ----
        if (blockIdx.x < 256){
            float* s_dtx = (float*)smem;                    // [2][CT*32]
            float* s_xcS = s_dtx + 2*CT*32;                 // [2][CT*16]
            float* s_Bv  = s_xcS + 2*CT*16;                 // [2][CT*16]
            float* s_Cv  = s_Bv  + 2*CT*16;                 // [2][CT*16]
            float* s_p   = s_Cv  + 2*CT*16;                 // [CT*16*17]
            float* s_Dp  = s_p   + CT*16*17;                // [16]
            const int bk  = blockIdx.x;
            const int b   = bk >> 5;
            const int dg  = bk & 31;
            const int dgb = dg*16;
            const int ld  = tid >> 4, n = tid & 15;
            const int d   = dgb + ld;
            const float A = -__expf(Alog[d*DSTATE + n]);
            const size_t tokbase = (size_t)b*SS;

            float r_dt[2], r_xc[2], r_bc[4];
            auto issue_loads = [&](int c){
                const int t0c = c*CT;
                #pragma unroll
                for (int r = 0; r < 2; ++r){
                    int e = tid + r*256;
                    int t = e >> 4, dd = e & 15;
                    size_t g = (tokbase + t0c + t)*DI + dgb + dd;
                    r_dt[r] = P.dtbuf[g];
                    r_xc[r] = P.xc[g];
                }
                #pragma unroll
                for (int r = 0; r < 4; ++r){
                    int e = tid + r*256;
                    int t = e >> 5, j = e & 31;
                    r_bc[r] = P.dtBC[(tokbase + t0c + t)*48 + 16 + j];
                }
            };
            auto commit = [&](int bu){
                #pragma unroll
                for (int r = 0; r < 2; ++r){
                    int e = tid + r*256;
                    int t = e >> 4, dd = e & 15;
                    s_dtx[bu*CT*32 + t*32 + dd*2]     = r_dt[r];
                    s_dtx[bu*CT*32 + t*32 + dd*2 + 1] = r_dt[r]*r_xc[r];
                    s_xcS[bu*CT*16 + e] = r_xc[r];
                }
                #pragma unroll
                for (int r = 0; r < 4; ++r){
                    int e = tid + r*256;
                    int t = e >> 5, j = e & 31;
                    if (j < 16) s_Bv[bu*CT*16 + t*16 + j]      = r_bc[r];
                    else        s_Cv[bu*CT*16 + t*16 + (j-16)] = r_bc[r];
                }
            };

            __syncthreads();
            issue_loads(0);
            commit(0);
            if (tid < 16) s_Dp[tid] = Dpp[dgb + tid];

            float h = 0.f;
            int buf = 0;
            for (int c = 0; c < NCH; ++c){
                __syncthreads();
                if (c+1 < NCH) issue_loads(c+1);
                const float* pdx = s_dtx + buf*CT*32 + ld*2;
                const float* pB  = s_Bv + buf*CT*16;
                const float* pC  = s_Cv + buf*CT*16;
                float* pp = s_p + ld*17 + n;
                #pragma unroll
                for (int t = 0; t < CT; ++t){
                    float2 dx = *(const float2*)(pdx + t*32);
                    float Bv  = pB[t*16 + n];
                    float dA  = __expf(dx.x * A);
                    h = dA*h + dx.y*Bv;
                    pp[t*272] = h * pC[t*16 + n];
                }
                __syncthreads();
                {
                    const int t0c = c*CT;
                    const float* pxc = s_xcS + buf*CT*16;
                    #pragma unroll
                    for (int r = 0; r < 2; ++r){
                        int e = tid + r*256;
                        int t = e >> 4, dd = e & 15;
                        const float* q = s_p + e*17;
                        float s = 0.f;
                        #pragma unroll
                        for (int k = 0; k < 16; ++k) s += q[k];
                        P.ybuf[(tokbase + t0c + t)*DI + dgb + dd] = s + pxc[e]*s_Dp[dd];
                    }
                }
                if (c+1 < NCH) commit(buf^1);
                buf ^= 1;
            }
        }
        __threadfence(); grid.sync();

        // ---- outproj + residual (384 vtiles) ----
        for (int vb = blockIdx.x; vb < 384; vb += gridDim.x){
            const int bx = vb >> 1, by = vb & 1;
            __syncthreads();
            u16* sA = (u16*)smem;
            {
                const int m = tid >> 4, p = tid & 15, e0 = p*32;
                const int row = bx*16 + m;
                const float* yp = P.ybuf + (size_t)row*DI + e0;
                const float* sp = P.sz   + (size_t)row*DI + e0;
                unsigned* dp = (unsigned*)sA + (m*520 + e0)/2;
                #pragma unroll
                for (int i = 0; i < 8; ++i){
                    float4 yv = *(const float4*)(yp + i*4);
                    float4 sv = *(const float4*)(sp + i*4);
                    dp[i*2]   = pack2(yv.x*sv.x, yv.y*sv.y);
                    dp[i*2+1] = pack2(yv.z*sv.z, yv.w*sv.w);
                }
            }
            __syncthreads();
            const int w = tid >> 6, l = tid & 63;
            f32x4 acc[2] = {{0,0,0,0},{0,0,0,0}};
            const u16* ap0 = sA + (l&15)*520 + (l>>4)*8;
            #pragma unroll
            for (int kc = 0; kc < 16; ++kc){
                short8 a = *(const short8*)(ap0 + kc*32);
                #pragma unroll
                for (int i = 0; i < 2; ++i){
                    int ntg = by*8 + w*2 + i;
                    short8 b8 = *(const short8*)(outsw + ((size_t)(ntg*16 + kc)*64 + l)*8);
                    acc[i] = __builtin_amdgcn_mfma_f32_16x16x32_bf16(a, b8, acc[i], 0,0,0);
                }
            }
            const int mrow0 = bx*16 + (l>>4)*4;
            #pragma unroll
            for (int i = 0; i < 2; ++i){
                int col = (by*8 + w*2 + i)*16 + (l&15);
                #pragma unroll
                for (int r = 0; r < 4; ++r)
                    P.residual[(mrow0+r)*DM + col] += acc[i][r];
            }
        }
        __threadfence(); grid.sync();
    }

    // ---------------- heads (1024 vblocks) ----------------
    for (int vb = blockIdx.x; vb < 1024; vb += gridDim.x){
        __syncthreads();
        float* x1 = (float*)smem;
        float* x2 = x1 + DM;
        float* scp = x2 + DM;
        float* partf = scp + 2;       // [2][4]
        const int b = vb >> 7, l = vb & 127;
        const int tok1 = b*SS + 3*l + 1;
        const int tok2 = tok1 + 1;
        float v1 = P.residual[tok1*DM + tid];
        float v2 = P.residual[tok2*DM + tid];
        {
            float s1 = v1*v1, s2 = v2*v2;
            #pragma unroll
            for (int off = 32; off >= 1; off >>= 1){
                s1 += __shfl_xor(s1, off, 64);
                s2 += __shfl_xor(s2, off, 64);
            }
            if ((tid & 63) == 0){ partf[0*4 + (tid>>6)] = s1; partf[1*4 + (tid>>6)] = s2; }
        }
        __syncthreads();
        if (tid < 2){
            float s = partf[tid*4+0]+partf[tid*4+1]+partf[tid*4+2]+partf[tid*4+3];
            scp[tid] = rsqrtf(s * (1.f/DM) + 1e-5f);
        }
        __syncthreads();
        float nw = P.fnorm_w[tid];
        x1[tid] = v1 * scp[0] * nw;
        x2[tid] = v2 * scp[1] * nw;
        __syncthreads();
        const int wv = tid >> 6, ln = tid & 63;
        for (int oi = wv; oi < 9; oi += 4){
            float a = 0.f;
            if (oi < 6){
                #pragma unroll
                for (int k = 0; k < 4; ++k){ int e = ln + 64*k; a += x2[e] * P.ps_W[e*6 + oi]; }
            } else {
                int j = oi - 6;
                #pragma unroll
                for (int k = 0; k < 4; ++k){ int e = ln + 64*k; a += x1[e] * P.pa_W[e*3 + j]; }
            }
            #pragma unroll
            for (int off = 32; off >= 1; off >>= 1) a += __shfl_xor(a, off, 64);
            if (ln == 0){
                float r; int idx;
                if (oi < 6){
                    r = a + P.ps_b[oi];
                    idx = (b*LL + l)*6 + oi;
                } else {
                    int j = oi - 6;
                    r = tanhf(a + P.pa_b[j]);
                    idx = BB*LL*6 + (b*LL + l)*3 + j;
                }
                if (f) ((u16*)P.out)[idx] = f2bf(r);
                else   ((float*)P.out)[idx] = r;
            }
        }
    }
}

// ===========================================================================
// Discrete fallback kernels (round-8 path) — used if cooperative launch fails
// ===========================================================================
__global__ __launch_bounds__(256) void k_prep(PrepArgs a,
                                              const unsigned* __restrict__ nwraw,
                                              float* __restrict__ dst){
    const int f = get_flag(nwraw);
    const int bk = blockIdx.x;
    if (bk < SWZ_NB){
        int gid = bk*256 + threadIdx.x;
        #pragma unroll 1
        for (int s = 0; s < 13; ++s){
            int fr = a.sd[s].frags;
            if (gid < fr){
                const int N = a.sd[s].N;
                const int l = gid & 63;
                const int rest = gid >> 6;
                const int kcn = a.sd[s].K >> 5;
                const int kc = rest % kcn;
                const int nt = rest / kcn;
                const int n  = nt*16 + (l & 15);
                const int k0 = kc*32 + (l >> 4)*8;
                u16 tmp[8];
                if (f){
                    const u16* src = (const u16*)a.sd[s].src;
                    #pragma unroll
                    for (int j = 0; j < 8; ++j) tmp[j] = src[(size_t)(k0+j)*N + n];
                } else {
                    const float* src = (const float*)((const char*)a.sd[s].src
                                                      + (size_t)g_soff[s]*2);
                    #pragma unroll
                    for (int j = 0; j < 8; ++j) tmp[j] = f2bf(src[(size_t)(k0+j)*N + n]);
                }
                *(short8*)(a.sd[s].dst + (size_t)gid*8) = *(short8*)tmp;
                return;
            }
            gid -= fr;
        }
    } else {
        const int stride = CNV_NB * 256;
        const int tid0 = (bk - SWZ_NB)*256 + threadIdx.x;
        #pragma unroll 1
        for (int s = 0; s < 23; ++s){
            const int n = a.cn[s];
            float* d = dst + a.coff[s];
            if (f){
                const u16* p = (const u16*)a.csrc[s];
                for (int i = tid0; i < n; i += stride) d[i] = bf(p[i]);
            } else {
                const float* p = (const float*)a.csrc[s];
                for (int i = tid0; i < n; i += stride) d[i] = p[i];
            }
        }
    }
}

__global__ __launch_bounds__(256) void k_embed_mfma(
    const float* __restrict__ states, const float* __restrict__ actions,
    const float* __restrict__ goal, const int* __restrict__ tsteps,
    const float* __restrict__ te_W, const float* __restrict__ se_W, const float* __restrict__ se_b,
    const float* __restrict__ ge_W, const float* __restrict__ ge_b,
    const float* __restrict__ ae_W, const float* __restrict__ ae_b,
    const u16* __restrict__ bbsw, const float* __restrict__ bb_b,
    float* __restrict__ residual)
{
    __shared__ u16 sA[32*264];
    const int tid = threadIdx.x;
    {
        const int m = tid >> 3, p = tid & 7, e0 = p*32;
        const int token = blockIdx.x*32 + m;
        const int b = token / SS, t = token % SS;
        const int slot = t % 3, step = t / 3;
        const int ts = tsteps[b*LL + step];
        float v[32];
        const float* tp = te_W + ts*EE + e0;
        #pragma unroll
        for (int i = 0; i < 8; ++i) *(float4*)(&v[i*4]) = *(const float4*)(tp + i*4);
        const float *bias, *Wp, *g; int nk;
        if (slot == 0){ bias = ge_b; Wp = ge_W; g = goal    + (b*LL+step)*6; nk = 6; }
        else if (slot == 1){ bias = se_b; Wp = se_W; g = states + (b*LL+step)*6; nk = 6; }
        else { bias = ae_b; Wp = ae_W; g = actions + (b*LL+step)*3; nk = 3; }
        #pragma unroll
        for (int i = 0; i < 8; ++i){
            float4 bv = *(const float4*)(bias + e0 + i*4);
            v[i*4]+=bv.x; v[i*4+1]+=bv.y; v[i*4+2]+=bv.z; v[i*4+3]+=bv.w;
        }
        for (int k = 0; k < nk; ++k){
            float gv = g[k];
            const float* wr = Wp + k*EE + e0;
            #pragma unroll
            for (int i = 0; i < 8; ++i){
                float4 wv = *(const float4*)(wr + i*4);
                v[i*4]+=gv*wv.x; v[i*4+1]+=gv*wv.y; v[i*4+2]+=gv*wv.z; v[i*4+3]+=gv*wv.w;
            }
        }
        unsigned* dp = (unsigned*)sA + (m*264 + e0)/2;
        #pragma unroll
        for (int i = 0; i < 16; ++i) dp[i] = pack2(v[2*i], v[2*i+1]);
    }
    __syncthreads();
    const int w = tid >> 6, l = tid & 63;
    const int mt = w >> 1, nq = w & 1;
    f32x4 acc[4] = {{0,0,0,0},{0,0,0,0},{0,0,0,0},{0,0,0,0}};
    const u16* ap0 = sA + (mt*16 + (l&15))*264 + (l>>4)*8;
    #pragma unroll
    for (int kc = 0; kc < 8; ++kc){
        short8 a = *(const short8*)(ap0 + kc*32);
        #pragma unroll
        for (int nt = 0; nt < 4; ++nt){
            int ntg = blockIdx.y*8 + nq*4 + nt;
            short8 b8 = *(const short8*)(bbsw + ((size_t)(ntg*8 + kc)*64 + l)*8);
            acc[nt] = __builtin_amdgcn_mfma_f32_16x16x32_bf16(a, b8, acc[nt], 0,0,0);
        }
    }
    const int mrow0 = blockIdx.x*32 + mt*16 + (l>>4)*4;
    #pragma unroll
    for (int nt = 0; nt < 4; ++nt){
        int col = (blockIdx.y*8 + nq*4 + nt)*16 + (l&15);
        float bb = bb_b[col];
        #pragma unroll
        for (int r = 0; r < 4; ++r)
            residual[(mrow0+r)*DM + col] = acc[nt][r] + bb;
    }
}

__global__ __launch_bounds__(256) void k_rms_inproj_mfma(
    const float* __restrict__ residual, const float* __restrict__ norm_w,
    const u16* __restrict__ Wsw,
    float* __restrict__ xc_raw, float* __restrict__ sz)
{
    __shared__ u16 sA[32*264];
    const int tid = threadIdx.x;
    {
        const int m = tid >> 3, p = tid & 7, e0 = p*32;
        const int row = blockIdx.x*32 + m;
        float v[32];
        const float* rp = residual + row*DM + e0;
        #pragma unroll
        for (int i = 0; i < 8; ++i) *(float4*)(&v[i*4]) = *(const float4*)(rp + i*4);
        float s = 0.f;
        #pragma unroll
        for (int i = 0; i < 32; ++i) s += v[i]*v[i];
        s += __shfl_xor(s,1,64); s += __shfl_xor(s,2,64); s += __shfl_xor(s,4,64);
        const float scale = rsqrtf(s*(1.f/DM) + 1e-5f);
        const float* nwp = norm_w + e0;
        unsigned* dp = (unsigned*)sA + (m*264 + e0)/2;
        #pragma unroll
        for (int i = 0; i < 16; ++i)
            dp[i] = pack2(v[2*i]*scale*nwp[2*i], v[2*i+1]*scale*nwp[2*i+1]);
    }
    __syncthreads();
    const int w = tid >> 6, l = tid & 63;
    const int mt = w >> 1, nq = w & 1;
    f32x4 acc[4] = {{0,0,0,0},{0,0,0,0},{0,0,0,0},{0,0,0,0}};
    const u16* ap0 = sA + (mt*16 + (l&15))*264 + (l>>4)*8;
    #pragma unroll
    for (int kc = 0; kc < 8; ++kc){
        short8 a = *(const short8*)(ap0 + kc*32);
        #pragma unroll
        for (int nt = 0; nt < 4; ++nt){
            int ntg = blockIdx.y*8 + nq*4 + nt;
            short8 b8 = *(const short8*)(Wsw + ((size_t)(ntg*8 + kc)*64 + l)*8);
            acc[nt] = __builtin_amdgcn_mfma_f32_16x16x32_bf16(a, b8, acc[nt], 0,0,0);
        }
    }
    const int mrow0 = blockIdx.x*32 + mt*16 + (l>>4)*4;
    if (blockIdx.y < 4){
        #pragma unroll
        for (int nt = 0; nt < 4; ++nt){
            int col = (blockIdx.y*8 + nq*4 + nt)*16 + (l&15);
            #pragma unroll
            for (int r = 0; r < 4; ++r)
                xc_raw[(mrow0+r)*DI + col] = acc[nt][r];
        }
    } else {
        #pragma unroll
        for (int nt = 0; nt < 4; ++nt){
            int col = (blockIdx.y*8 + nq*4 + nt)*16 + (l&15) - DI;
            #pragma unroll
            for (int r = 0; r < 4; ++r){
                float z = acc[nt][r];
                sz[(mrow0+r)*DI + col] = z / (1.f + __expf(-z));
            }
        }
    }
}

__global__ __launch_bounds__(256) void k_conv_mfma(
    const float* __restrict__ xc_raw,
    const float* __restrict__ conv_w, const float* __restrict__ conv_b,
    const u16* __restrict__ xpsw,
    const float* __restrict__ dt_W, const float* __restrict__ dt_b,
    float* __restrict__ xc, float* __restrict__ dtBC, float* __restrict__ dt)
{
    __shared__ u16 sxc[16*520];
    __shared__ float sdtbc[16*64];
    const int tid = threadIdx.x;
    const int base = blockIdx.x * 16;
    const int t0 = base % SS;
    #pragma unroll
    for (int half = 0; half < 2; ++half){
        const int d = tid + half*256;
        const float w0 = conv_w[d*4+0], w1 = conv_w[d*4+1];
        const float w2 = conv_w[d*4+2], w3 = conv_w[d*4+3];
        const float cb = conv_b[d];
        const float* rp = xc_raw + (size_t)base*DI + d;
        float xm3=0.f, xm2=0.f, xm1=0.f;
        if (t0 > 0){
            xm3 = rp[-3*DI]; xm2 = rp[-2*DI]; xm1 = rp[-DI];
        }
        #pragma unroll
        for (int tk = 0; tk < 16; ++tk){
            float x0 = rp[tk*DI];
            float a = cb + w0*xm3 + w1*xm2 + w2*xm1 + w3*x0;
            float s = a / (1.f + __expf(-a));
            xc[(size_t)(base+tk)*DI + d] = s;
            sxc[tk*520 + d] = f2bf(s);
            xm3 = xm2; xm2 = xm1; xm1 = x0;
        }
    }
    __syncthreads();
    const int w = tid >> 6, l = tid & 63;
    if (w < 3){
        f32x4 acc = {0,0,0,0};
        const u16* ap0 = sxc + (l&15)*520 + (l>>4)*8;
        #pragma unroll
        for (int kc = 0; kc < 16; ++kc){
            short8 a = *(const short8*)(ap0 + kc*32);
            short8 b8 = *(const short8*)(xpsw + ((size_t)(w*16 + kc)*64 + l)*8);
            acc = __builtin_amdgcn_mfma_f32_16x16x32_bf16(a, b8, acc, 0,0,0);
        }
        #pragma unroll
        for (int r = 0; r < 4; ++r)
            sdtbc[((l>>4)*4 + r)*64 + w*16 + (l&15)] = acc[r];
    }
    __syncthreads();
    #pragma unroll
    for (int r = 0; r < 2; ++r){
        int i = tid + r*256;
        int t = i >> 5, j = i & 31;
        dtBC[(size_t)(base+t)*48 + 16 + j] = sdtbc[t*64 + 16 + j];
    }
    #pragma unroll
    for (int half = 0; half < 2; ++half){
        const int d = tid + half*256;
        const float db = dt_b[d];
        float wr[16];
        #pragma unroll
        for (int r = 0; r < 16; ++r) wr[r] = dt_W[r*DI + d];
        #pragma unroll
        for (int tk = 0; tk < 16; ++tk){
            float a = db;
            #pragma unroll
            for (int r = 0; r < 16; ++r) a += sdtbc[tk*64 + r] * wr[r];
            float sp = (a > 15.f) ? a : __logf(1.f + __expf(a));
            dt[(size_t)(base+tk)*DI + d] = sp;
        }
    }
}

__global__ __launch_bounds__(256) void k_scan(
    const float* __restrict__ dt, const float* __restrict__ dtBC,
    const float* __restrict__ xc,
    const float* __restrict__ A_log, const float* __restrict__ Dp,
    float* __restrict__ y)
{
    __shared__ float s_dtx[2][CT*32];
    __shared__ float s_xc [2][CT*16];
    __shared__ float s_B [2][CT*16];
    __shared__ float s_C [2][CT*16];
    __shared__ float s_p [CT*16*17];
    __shared__ float s_Dp[16];
    const int tid = threadIdx.x;
    const int bk  = blockIdx.x;
    const int b   = bk >> 5;
    const int dg  = bk & 31;
    const int dgb = dg*16;
    const int ld  = tid >> 4, n = tid & 15;
    const int d   = dgb + ld;
    const float A = -__expf(A_log[d*DSTATE + n]);
    const size_t tokbase = (size_t)b*SS;
    float r_dt[2], r_xc[2], r_bc[4];
    auto issue_loads = [&](int c){
        const int t0 = c*CT;
        #pragma unroll
        for (int r = 0; r < 2; ++r){
            int e = tid + r*256;
            int t = e >> 4, dd = e & 15;
            size_t g = (tokbase + t0 + t)*DI + dgb + dd;
            r_dt[r] = dt[g];
            r_xc[r] = xc[g];
        }
        #pragma unroll
        for (int r = 0; r < 4; ++r){
            int e = tid + r*256;
            int t = e >> 5, j = e & 31;
            r_bc[r] = dtBC[(tokbase + t0 + t)*48 + 16 + j];
        }
    };
    auto commit = [&](int bu){
        #pragma unroll
        for (int r = 0; r < 2; ++r){
            int e = tid + r*256;
            int t = e >> 4, dd = e & 15;
            s_dtx[bu][t*32 + dd*2]     = r_dt[r];
            s_dtx[bu][t*32 + dd*2 + 1] = r_dt[r]*r_xc[r];
            s_xc[bu][e] = r_xc[r];
        }
        #pragma unroll
        for (int r = 0; r < 4; ++r){
            int e = tid + r*256;
            int t = e >> 5, j = e & 31;
            if (j < 16) s_B[bu][t*16 + j]      = r_bc[r];
            else        s_C[bu][t*16 + (j-16)] = r_bc[r];
        }
    };
    issue_loads(0);
    commit(0);
    if (tid < 16) s_Dp[tid] = Dp[dgb + tid];
    float h = 0.f;
    int buf = 0;
    for (int c = 0; c < NCH; ++c){
        __syncthreads();
        if (c+1 < NCH) issue_loads(c+1);
        const float* pdx = s_dtx[buf] + ld*2;
        const float* pB  = s_B[buf];
        const float* pC  = s_C[buf];
        float* pp = s_p + ld*17 + n;
        #pragma unroll
        for (int t = 0; t < CT; ++t){
            float2 dx = *(const float2*)(pdx + t*32);
            float Bv  = pB[t*16 + n];
            float dA  = __expf(dx.x * A);
            h = dA*h + dx.y*Bv;
            pp[t*272] = h * pC[t*16 + n];
        }
        __syncthreads();
        {
            const int t0 = c*CT;
            const float* pxc = s_xc[buf];
            #pragma unroll
            for (int r = 0; r < 2; ++r){
                int e = tid + r*256;
                int t = e >> 4, dd = e & 15;
                const float* q = s_p + e*17;
                float s = 0.f;
                #pragma unroll
                for (int k = 0; k < 16; ++k) s += q[k];
                y[(tokbase + t0 + t)*DI + dgb + dd] = s + pxc[e]*s_Dp[dd];
            }
        }
        if (c+1 < NCH) commit(buf^1);
        buf ^= 1;
    }
}

__global__ __launch_bounds__(256) void k_outproj_mfma(
    const float* __restrict__ y, const float* __restrict__ szb,
    const u16* __restrict__ Wsw, float* __restrict__ residual)
{
    __shared__ u16 sA[16*520];
    const int tid = threadIdx.x;
    {
        const int m = tid >> 4, p = tid & 15, e0 = p*32;
        const int row = blockIdx.x*16 + m;
        const float* yp = y   + (size_t)row*DI + e0;
        const float* sp = szb + (size_t)row*DI + e0;
        unsigned* dp = (unsigned*)sA + (m*520 + e0)/2;
        #pragma unroll
        for (int i = 0; i < 8; ++i){
            float4 yv = *(const float4*)(yp + i*4);
            float4 sv = *(const float4*)(sp + i*4);
            dp[i*2]   = pack2(yv.x*sv.x, yv.y*sv.y);
            dp[i*2+1] = pack2(yv.z*sv.z, yv.w*sv.w);
        }
    }
    __syncthreads();
    const int w = tid >> 6, l = tid & 63;
    f32x4 acc[2] = {{0,0,0,0},{0,0,0,0}};
    const u16* ap0 = sA + (l&15)*520 + (l>>4)*8;
    #pragma unroll
    for (int kc = 0; kc < 16; ++kc){
        short8 a = *(const short8*)(ap0 + kc*32);
        #pragma unroll
        for (int i = 0; i < 2; ++i){
            int ntg = blockIdx.y*8 + w*2 + i;
            short8 b8 = *(const short8*)(Wsw + ((size_t)(ntg*16 + kc)*64 + l)*8);
            acc[i] = __builtin_amdgcn_mfma_f32_16x16x32_bf16(a, b8, acc[i], 0,0,0);
        }
    }
    const int mrow0 = blockIdx.x*16 + (l>>4)*4;
    #pragma unroll
    for (int i = 0; i < 2; ++i){
        int col = (blockIdx.y*8 + w*2 + i)*16 + (l&15);
        #pragma unroll
        for (int r = 0; r < 4; ++r)
            residual[(mrow0+r)*DM + col] += acc[i][r];
    }
}

__global__ __launch_bounds__(256) void k_heads(
    const float* __restrict__ residual, const float* __restrict__ fnorm_w,
    const float* __restrict__ ps_W, const float* __restrict__ ps_b,
    const float* __restrict__ pa_W, const float* __restrict__ pa_b,
    const unsigned* __restrict__ nwraw, void* __restrict__ out)
{
    __shared__ float x1[DM], x2[DM];
    __shared__ float sc[2];
    __shared__ float part[2][4];
    const int tid = threadIdx.x;
    const int bl = blockIdx.x;
    const int b = bl >> 7, l = bl & 127;
    const int fl = get_flag(nwraw);
    const int tok1 = b*SS + 3*l + 1;
    const int tok2 = tok1 + 1;
    float v1 = residual[tok1*DM + tid];
    float v2 = residual[tok2*DM + tid];
    {
        float s1 = v1*v1, s2 = v2*v2;
        #pragma unroll
        for (int off = 32; off >= 1; off >>= 1){
            s1 += __shfl_xor(s1, off, 64);
            s2 += __shfl_xor(s2, off, 64);
        }
        if ((tid & 63) == 0){ part[0][tid>>6] = s1; part[1][tid>>6] = s2; }
    }
    __syncthreads();
    if (tid < 2){
        float s = part[tid][0]+part[tid][1]+part[tid][2]+part[tid][3];
        sc[tid] = rsqrtf(s * (1.f/DM) + 1e-5f);
    }
    __syncthreads();
    float nw = fnorm_w[tid];
    x1[tid] = v1 * sc[0] * nw;
    x2[tid] = v2 * sc[1] * nw;
    __syncthreads();
    const int wv = tid >> 6, ln = tid & 63;
    for (int oi = wv; oi < 9; oi += 4){
        float a = 0.f;
        if (oi < 6){
            #pragma unroll
            for (int k = 0; k < 4; ++k){ int e = ln + 64*k; a += x2[e] * ps_W[e*6 + oi]; }
        } else {
            int j = oi - 6;
            #pragma unroll
            for (int k = 0; k < 4; ++k){ int e = ln + 64*k; a += x1[e] * pa_W[e*3 + j]; }
        }
        #pragma unroll
        for (int off = 32; off >= 1; off >>= 1) a += __shfl_xor(a, off, 64);
        if (ln == 0){
            float r; int idx;
            if (oi < 6){
                r = a + ps_b[oi];
                idx = (b*LL + l)*6 + oi;
            } else {
                int j = oi - 6;
                r = tanhf(a + pa_b[j]);
                idx = BB*LL*6 + (b*LL + l)*3 + j;
            }
            if (fl) ((u16*)out)[idx] = f2bf(r);
            else    ((float*)out)[idx] = r;
        }
    }
}

// ---------------------------------------------------------------------------
extern "C" void kernel_launch(void* const* d_in, const int* in_sizes, int n_in,
                              void* d_out, int out_size, void* d_ws, size_t ws_size,
                              hipStream_t stream)
{
    const int* tsteps = (const int*)d_in[3];
    const unsigned* nwraw = (const unsigned*)d_in[13];

    float* fin = (float*)d_ws;

    const int cidx[23] = {0,1,2,4,5,6,7,8,9,10,12,13,15,16,18,19,20,21,23,24,25,26,27};
    PrepArgs prep;
    const float* fp[28];
    for (int i = 0; i < 28; ++i) fp[i] = nullptr;
    int cur = 0;
    for (int i = 0; i < 23; ++i){
        int gi = cidx[i];
        prep.csrc[i] = d_in[gi];
        prep.cn[i]   = in_sizes[gi];
        prep.coff[i] = cur;
        fp[gi] = fin + cur;
        cur += in_sizes[gi];
        cur = (cur + 3) & ~3;
    }
    float* act = fin + cur;

    float* residual = act;            act += BT*DM;
    float* xc_raw   = act;            act += BT*DI;
    float* sz       = act;            act += BT*DI;
    float* xc       = act;            act += BT*DI;
    float* dtbuf    = act;            act += BT*DI;
    float* ybuf     = act;            act += BT*DI;
    float* dtBC     = act;            act += BT*48;

    u16* wsb    = (u16*)act;
    u16* bb_sw  = wsb;
    u16* in_sw  = bb_sw + 65536;
    u16* out_sw = in_sw + 4*262144;
    u16* xp_sw  = out_sw + 4*131072;

    const int soff[13] = {0, 0, 262144, 524288, 786432,
                          0, 131072, 262144, 393216,
                          0, 24576, 49152, 73728};
    prep.sd[0] = { d_in[11], bb_sw, 256, 256, (256/16)*(256/32)*64 };
    for (int i = 0; i < 4; ++i)
        prep.sd[1+i] = { d_in[14], in_sw + i*262144, 256, 1024,
                         (1024/16)*(256/32)*64 };
    for (int i = 0; i < 4; ++i)
        prep.sd[5+i] = { d_in[22], out_sw + i*131072, 512, 256,
                         (256/16)*(512/32)*64 };
    for (int i = 0; i < 4; ++i)
        prep.sd[9+i] = { d_in[17], xp_sw + i*24576, 512, 48,
                         (48/16)*(512/32)*64 };
    for (int i = 0; i < 13; ++i)
        prep.sd[i].src = (const void*)((const char*)prep.sd[i].src + (size_t)soff[i]*2);

    // ---- try cooperative mega-kernel ----
    Params P;
    P.pa = prep;
    P.tsteps = tsteps;  P.nwraw = nwraw;  P.fin = fin;
    P.states = fp[0];   P.actions = fp[1]; P.goal = fp[2];
    P.te_W = fp[4];     P.se_W = fp[5];    P.se_b = fp[6];
    P.ge_W = fp[7];     P.ge_b = fp[8];    P.ae_W = fp[9];  P.ae_b = fp[10];
    P.bb_b = fp[12];    P.norm_w = fp[13];
    P.conv_w = fp[15];  P.conv_b = fp[16];
    P.dt_W = fp[18];    P.dt_b = fp[19];
    P.A_log = fp[20];   P.Dp = fp[21];
    P.fnorm_w = fp[23]; P.ps_W = fp[24];   P.ps_b = fp[25];
    P.pa_W = fp[26];    P.pa_b = fp[27];
    P.bb_sw = bb_sw;    P.in_sw = in_sw;   P.out_sw = out_sw; P.xp_sw = xp_sw;
    P.residual = residual; P.xc_raw = xc_raw; P.sz = sz; P.xc = xc;
    P.dtbuf = dtbuf;    P.ybuf = ybuf;     P.dtBC = dtBC;
    P.out = d_out;

    void* args[] = { &P };
    hipError_t err = hipLaunchCooperativeKernel((const void*)k_mega,
                                                dim3(512), dim3(256),
                                                args, 0, stream);
    if (err == hipSuccess) return;
    (void)hipGetLastError();   // clear sticky error

    // ---- fallback: discrete round-8 path ----
    k_prep<<<SWZ_NB + CNV_NB, 256, 0, stream>>>(prep, nwraw, fin);
    k_embed_mfma<<<dim3(96,2), 256, 0, stream>>>(fp[0], fp[1], fp[2], tsteps,
        fp[4], fp[5], fp[6], fp[7], fp[8], fp[9], fp[10], bb_sw, fp[12], residual);
    for (int lyr = 0; lyr < NL; ++lyr){
        k_rms_inproj_mfma<<<dim3(96,8), 256, 0, stream>>>(residual, fp[13] + lyr*DM,
            in_sw + lyr*262144, xc_raw, sz);
        k_conv_mfma<<<BT/16, 256, 0, stream>>>(xc_raw, fp[15] + lyr*DI*4,
            fp[16] + lyr*DI, xp_sw + lyr*24576, fp[18] + lyr*RK*DI, fp[19] + lyr*DI,
            xc, dtBC, dtbuf);
        k_scan<<<256, 256, 0, stream>>>(dtbuf, dtBC, xc,
            fp[20] + lyr*DI*DSTATE, fp[21] + lyr*DI, ybuf);
        k_outproj_mfma<<<dim3(192,2), 256, 0, stream>>>(ybuf, sz,
            out_sw + lyr*131072, residual);
    }
    k_heads<<<BB*LL, 256, 0, stream>>>(residual, fp[23], fp[24], fp[25], fp[26], fp[27],
                                       nwraw, (u16*)d_out);
}

// Round 10
// 369.057 us; speedup vs baseline: 7.3244x; 7.3244x over previous
//
#include <hip/hip_runtime.h>
#include <hip/hip_bf16.h>
#include <math.h>

#define BB 8
#define LL 128
#define SS 384        // 3*L
#define BT 3072       // B*S
#define EE 256
#define DM 256
#define DI 512
#define DSTATE 16
#define RK 16
#define NL 4

typedef unsigned short u16;
typedef __attribute__((ext_vector_type(8))) short short8;
typedef __attribute__((ext_vector_type(4))) float f32x4;

__device__ __forceinline__ float bf(const u16 v){
    union { unsigned u; float f; } c; c.u = ((unsigned)v) << 16; return c.f;
}
__device__ __forceinline__ u16 f2bf(float f){
    union { float f; unsigned u; } c; c.f = f;
    unsigned x = c.u;
    unsigned r = (x >> 16) & 1u;
    x += 0x7fffu + r;
    return (u16)(x >> 16);
}
__device__ __forceinline__ unsigned pack2(float a, float b){
    return ((unsigned)f2bf(a)) | (((unsigned)f2bf(b)) << 16);
}
__device__ __forceinline__ int get_flag(const unsigned* nwraw){
    return (nwraw[0] == 0x3F800000u) ? 0 : 1;   // 1 = bf16 inputs
}

// ---------------------------------------------------------------------------
// k_prep: convert small fp tensors to fp32 + swizzle big weights (raw src)
// into MFMA B-fragment order. Host bakes elemoff*2 bytes into src (exact for
// bf16); f32 path adds elemoff*2 more bytes via g_soff.
// ---------------------------------------------------------------------------
#define SWZ_NB 848     // 217088 frags / 256
#define CNV_NB 64

__device__ __constant__ int g_soff[13] = {0, 0, 262144, 524288, 786432,
                                          0, 131072, 262144, 393216,
                                          0, 24576, 49152, 73728};

struct SwzDesc { const void* src; u16* dst; int K; int N; int frags; };
struct PrepArgs {
    const void* csrc[23]; int cn[23]; int coff[23];
    SwzDesc sd[13];
};

__global__ __launch_bounds__(256) void k_prep(PrepArgs a,
                                              const unsigned* __restrict__ nwraw,
                                              float* __restrict__ dst){
    const int f = get_flag(nwraw);
    const int bk = blockIdx.x;
    if (bk < SWZ_NB){
        int gid = bk*256 + threadIdx.x;
        #pragma unroll 1
        for (int s = 0; s < 13; ++s){
            int fr = a.sd[s].frags;
            if (gid < fr){
                const int N = a.sd[s].N;
                const int l = gid & 63;
                const int rest = gid >> 6;
                const int kcn = a.sd[s].K >> 5;
                const int kc = rest % kcn;
                const int nt = rest / kcn;
                const int n  = nt*16 + (l & 15);
                const int k0 = kc*32 + (l >> 4)*8;
                u16 tmp[8];
                if (f){
                    const u16* src = (const u16*)a.sd[s].src;
                    #pragma unroll
                    for (int j = 0; j < 8; ++j) tmp[j] = src[(size_t)(k0+j)*N + n];
                } else {
                    const float* src = (const float*)((const char*)a.sd[s].src
                                                      + (size_t)g_soff[s]*2);
                    #pragma unroll
                    for (int j = 0; j < 8; ++j) tmp[j] = f2bf(src[(size_t)(k0+j)*N + n]);
                }
                *(short8*)(a.sd[s].dst + (size_t)gid*8) = *(short8*)tmp;
                return;
            }
            gid -= fr;
        }
    } else {
        const int stride = CNV_NB * 256;
        const int tid0 = (bk - SWZ_NB)*256 + threadIdx.x;
        #pragma unroll 1
        for (int s = 0; s < 23; ++s){
            const int n = a.cn[s];
            float* d = dst + a.coff[s];
            if (f){
                const u16* p = (const u16*)a.csrc[s];
                for (int i = tid0; i < n; i += stride) d[i] = bf(p[i]);
            } else {
                const float* p = (const float*)a.csrc[s];
                for (int i = tid0; i < n; i += stride) d[i] = p[i];
            }
        }
    }
}

// ---------------------------------------------------------------------------
// K1: embeddings + interleave + bb_in GEMM (MFMA) -> residual
// ---------------------------------------------------------------------------
__global__ __launch_bounds__(256) void k_embed_mfma(
    const float* __restrict__ states, const float* __restrict__ actions,
    const float* __restrict__ goal, const int* __restrict__ tsteps,
    const float* __restrict__ te_W, const float* __restrict__ se_W, const float* __restrict__ se_b,
    const float* __restrict__ ge_W, const float* __restrict__ ge_b,
    const float* __restrict__ ae_W, const float* __restrict__ ae_b,
    const u16* __restrict__ bbsw, const float* __restrict__ bb_b,
    float* __restrict__ residual)
{
    __shared__ u16 sA[32*264];
    const int tid = threadIdx.x;
    {
        const int m = tid >> 3, p = tid & 7, e0 = p*32;
        const int token = blockIdx.x*32 + m;
        const int b = token / SS, t = token % SS;
        const int slot = t % 3, step = t / 3;
        const int ts = tsteps[b*LL + step];
        float v[32];
        const float* tp = te_W + ts*EE + e0;
        #pragma unroll
        for (int i = 0; i < 8; ++i) *(float4*)(&v[i*4]) = *(const float4*)(tp + i*4);
        const float *bias, *Wp, *g; int nk;
        if (slot == 0){ bias = ge_b; Wp = ge_W; g = goal    + (b*LL+step)*6; nk = 6; }
        else if (slot == 1){ bias = se_b; Wp = se_W; g = states + (b*LL+step)*6; nk = 6; }
        else { bias = ae_b; Wp = ae_W; g = actions + (b*LL+step)*3; nk = 3; }
        #pragma unroll
        for (int i = 0; i < 8; ++i){
            float4 bv = *(const float4*)(bias + e0 + i*4);
            v[i*4]+=bv.x; v[i*4+1]+=bv.y; v[i*4+2]+=bv.z; v[i*4+3]+=bv.w;
        }
        for (int k = 0; k < nk; ++k){
            float gv = g[k];
            const float* wr = Wp + k*EE + e0;
            #pragma unroll
            for (int i = 0; i < 8; ++i){
                float4 wv = *(const float4*)(wr + i*4);
                v[i*4]+=gv*wv.x; v[i*4+1]+=gv*wv.y; v[i*4+2]+=gv*wv.z; v[i*4+3]+=gv*wv.w;
            }
        }
        unsigned* dp = (unsigned*)sA + (m*264 + e0)/2;
        #pragma unroll
        for (int i = 0; i < 16; ++i) dp[i] = pack2(v[2*i], v[2*i+1]);
    }
    __syncthreads();
    const int w = tid >> 6, l = tid & 63;
    const int mt = w >> 1, nq = w & 1;
    f32x4 acc[4] = {{0,0,0,0},{0,0,0,0},{0,0,0,0},{0,0,0,0}};
    const u16* ap0 = sA + (mt*16 + (l&15))*264 + (l>>4)*8;
    #pragma unroll
    for (int kc = 0; kc < 8; ++kc){
        short8 a = *(const short8*)(ap0 + kc*32);
        #pragma unroll
        for (int nt = 0; nt < 4; ++nt){
            int ntg = blockIdx.y*8 + nq*4 + nt;
            short8 b8 = *(const short8*)(bbsw + ((size_t)(ntg*8 + kc)*64 + l)*8);
            acc[nt] = __builtin_amdgcn_mfma_f32_16x16x32_bf16(a, b8, acc[nt], 0,0,0);
        }
    }
    const int mrow0 = blockIdx.x*32 + mt*16 + (l>>4)*4;
    #pragma unroll
    for (int nt = 0; nt < 4; ++nt){
        int col = (blockIdx.y*8 + nq*4 + nt)*16 + (l&15);
        float bb = bb_b[col];
        #pragma unroll
        for (int r = 0; r < 4; ++r)
            residual[(mrow0+r)*DM + col] = acc[nt][r] + bb;
    }
}

// ---------------------------------------------------------------------------
// K2: RMSNorm + in_proj GEMM (256->1024) via MFMA. grid (96,8).
// ---------------------------------------------------------------------------
__global__ __launch_bounds__(256) void k_rms_inproj_mfma(
    const float* __restrict__ residual, const float* __restrict__ norm_w,
    const u16* __restrict__ Wsw,
    float* __restrict__ xc_raw, float* __restrict__ sz)
{
    __shared__ u16 sA[32*264];
    const int tid = threadIdx.x;
    {
        const int m = tid >> 3, p = tid & 7, e0 = p*32;
        const int row = blockIdx.x*32 + m;
        float v[32];
        const float* rp = residual + row*DM + e0;
        #pragma unroll
        for (int i = 0; i < 8; ++i) *(float4*)(&v[i*4]) = *(const float4*)(rp + i*4);
        float s = 0.f;
        #pragma unroll
        for (int i = 0; i < 32; ++i) s += v[i]*v[i];
        s += __shfl_xor(s,1,64); s += __shfl_xor(s,2,64); s += __shfl_xor(s,4,64);
        const float scale = rsqrtf(s*(1.f/DM) + 1e-5f);
        const float* nwp = norm_w + e0;
        unsigned* dp = (unsigned*)sA + (m*264 + e0)/2;
        #pragma unroll
        for (int i = 0; i < 16; ++i)
            dp[i] = pack2(v[2*i]*scale*nwp[2*i], v[2*i+1]*scale*nwp[2*i+1]);
    }
    __syncthreads();
    const int w = tid >> 6, l = tid & 63;
    const int mt = w >> 1, nq = w & 1;
    f32x4 acc[4] = {{0,0,0,0},{0,0,0,0},{0,0,0,0},{0,0,0,0}};
    const u16* ap0 = sA + (mt*16 + (l&15))*264 + (l>>4)*8;
    #pragma unroll
    for (int kc = 0; kc < 8; ++kc){
        short8 a = *(const short8*)(ap0 + kc*32);
        #pragma unroll
        for (int nt = 0; nt < 4; ++nt){
            int ntg = blockIdx.y*8 + nq*4 + nt;
            short8 b8 = *(const short8*)(Wsw + ((size_t)(ntg*8 + kc)*64 + l)*8);
            acc[nt] = __builtin_amdgcn_mfma_f32_16x16x32_bf16(a, b8, acc[nt], 0,0,0);
        }
    }
    const int mrow0 = blockIdx.x*32 + mt*16 + (l>>4)*4;
    if (blockIdx.y < 4){
        #pragma unroll
        for (int nt = 0; nt < 4; ++nt){
            int col = (blockIdx.y*8 + nq*4 + nt)*16 + (l&15);
            #pragma unroll
            for (int r = 0; r < 4; ++r)
                xc_raw[(mrow0+r)*DI + col] = acc[nt][r];
        }
    } else {
        #pragma unroll
        for (int nt = 0; nt < 4; ++nt){
            int col = (blockIdx.y*8 + nq*4 + nt)*16 + (l&15) - DI;
            #pragma unroll
            for (int r = 0; r < 4; ++r){
                float z = acc[nt][r];
                sz[(mrow0+r)*DI + col] = z / (1.f + __expf(-z));
            }
        }
    }
}

// ---------------------------------------------------------------------------
// K3: conv(4)+silu -> xc; xproj via MFMA (K=512,N=48); dt softplus.
// ---------------------------------------------------------------------------
__global__ __launch_bounds__(256) void k_conv_mfma(
    const float* __restrict__ xc_raw,
    const float* __restrict__ conv_w, const float* __restrict__ conv_b,
    const u16* __restrict__ xpsw,
    const float* __restrict__ dt_W, const float* __restrict__ dt_b,
    float* __restrict__ xc, float* __restrict__ dtBC, float* __restrict__ dt)
{
    __shared__ u16 sxc[16*520];
    __shared__ float sdtbc[16*64];
    const int tid = threadIdx.x;
    const int base = blockIdx.x * 16;
    const int t0 = base % SS;

    #pragma unroll
    for (int half = 0; half < 2; ++half){
        const int d = tid + half*256;
        const float w0 = conv_w[d*4+0], w1 = conv_w[d*4+1];
        const float w2 = conv_w[d*4+2], w3 = conv_w[d*4+3];
        const float cb = conv_b[d];
        const float* rp = xc_raw + (size_t)base*DI + d;
        float xm3=0.f, xm2=0.f, xm1=0.f;
        if (t0 > 0){
            xm3 = rp[-3*DI]; xm2 = rp[-2*DI]; xm1 = rp[-DI];
        }
        #pragma unroll
        for (int tk = 0; tk < 16; ++tk){
            float x0 = rp[tk*DI];
            float a = cb + w0*xm3 + w1*xm2 + w2*xm1 + w3*x0;
            float s = a / (1.f + __expf(-a));
            xc[(size_t)(base+tk)*DI + d] = s;
            sxc[tk*520 + d] = f2bf(s);
            xm3 = xm2; xm2 = xm1; xm1 = x0;
        }
    }
    __syncthreads();

    const int w = tid >> 6, l = tid & 63;
    if (w < 3){
        f32x4 acc = {0,0,0,0};
        const u16* ap0 = sxc + (l&15)*520 + (l>>4)*8;
        #pragma unroll
        for (int kc = 0; kc < 16; ++kc){
            short8 a = *(const short8*)(ap0 + kc*32);
            short8 b8 = *(const short8*)(xpsw + ((size_t)(w*16 + kc)*64 + l)*8);
            acc = __builtin_amdgcn_mfma_f32_16x16x32_bf16(a, b8, acc, 0,0,0);
        }
        #pragma unroll
        for (int r = 0; r < 4; ++r)
            sdtbc[((l>>4)*4 + r)*64 + w*16 + (l&15)] = acc[r];
    }
    __syncthreads();

    #pragma unroll
    for (int r = 0; r < 2; ++r){
        int i = tid + r*256;
        int t = i >> 5, j = i & 31;
        dtBC[(size_t)(base+t)*48 + 16 + j] = sdtbc[t*64 + 16 + j];
    }

    #pragma unroll
    for (int half = 0; half < 2; ++half){
        const int d = tid + half*256;
        const float db = dt_b[d];
        float wr[16];
        #pragma unroll
        for (int r = 0; r < 16; ++r) wr[r] = dt_W[r*DI + d];
        #pragma unroll
        for (int tk = 0; tk < 16; ++tk){
            float a = db;
            #pragma unroll
            for (int r = 0; r < 16; ++r) a += sdtbc[tk*64 + r] * wr[r];
            float sp = (a > 15.f) ? a : __logf(1.f + __expf(a));
            dt[(size_t)(base+tk)*DI + d] = sp;
        }
    }
}

// ---------------------------------------------------------------------------
// K5: selective scan; (dt, dt*xc) packed as float2 -> one ds_read_b64 in loop.
// ---------------------------------------------------------------------------
#define CT 32
#define NCH (SS/CT)   // 12

__global__ __launch_bounds__(256) void k_scan(
    const float* __restrict__ dt, const float* __restrict__ dtBC,
    const float* __restrict__ xc,
    const float* __restrict__ A_log, const float* __restrict__ Dp,
    float* __restrict__ y)
{
    __shared__ float s_dtx[2][CT*32];
    __shared__ float s_xc [2][CT*16];
    __shared__ float s_B [2][CT*16];
    __shared__ float s_C [2][CT*16];
    __shared__ float s_p [CT*16*17];
    __shared__ float s_Dp[16];

    const int tid = threadIdx.x;
    const int bk  = blockIdx.x;
    const int b   = bk >> 5;
    const int dg  = bk & 31;
    const int dgb = dg*16;
    const int ld  = tid >> 4, n = tid & 15;
    const int d   = dgb + ld;

    const float A = -__expf(A_log[d*DSTATE + n]);
    const size_t tokbase = (size_t)b*SS;

    float r_dt[2], r_xc[2], r_bc[4];

    auto issue_loads = [&](int c){
        const int t0 = c*CT;
        #pragma unroll
        for (int r = 0; r < 2; ++r){
            int e = tid + r*256;
            int t = e >> 4, dd = e & 15;
            size_t g = (tokbase + t0 + t)*DI + dgb + dd;
            r_dt[r] = dt[g];
            r_xc[r] = xc[g];
        }
        #pragma unroll
        for (int r = 0; r < 4; ++r){
            int e = tid + r*256;
            int t = e >> 5, j = e & 31;
            r_bc[r] = dtBC[(tokbase + t0 + t)*48 + 16 + j];
        }
    };
    auto commit = [&](int bu){
        #pragma unroll
        for (int r = 0; r < 2; ++r){
            int e = tid + r*256;
            int t = e >> 4, dd = e & 15;
            s_dtx[bu][t*32 + dd*2]     = r_dt[r];
            s_dtx[bu][t*32 + dd*2 + 1] = r_dt[r]*r_xc[r];
            s_xc[bu][e] = r_xc[r];
        }
        #pragma unroll
        for (int r = 0; r < 4; ++r){
            int e = tid + r*256;
            int t = e >> 5, j = e & 31;
            if (j < 16) s_B[bu][t*16 + j]      = r_bc[r];
            else        s_C[bu][t*16 + (j-16)] = r_bc[r];
        }
    };

    issue_loads(0);
    commit(0);
    if (tid < 16) s_Dp[tid] = Dp[dgb + tid];

    float h = 0.f;
    int buf = 0;
    for (int c = 0; c < NCH; ++c){
        __syncthreads();
        if (c+1 < NCH) issue_loads(c+1);
        const float* pdx = s_dtx[buf] + ld*2;
        const float* pB  = s_B[buf];
        const float* pC  = s_C[buf];
        float* pp = s_p + ld*17 + n;
        #pragma unroll
        for (int t = 0; t < CT; ++t){
            float2 dx = *(const float2*)(pdx + t*32);
            float Bv  = pB[t*16 + n];
            float dA  = __expf(dx.x * A);
            h = dA*h + dx.y*Bv;
            pp[t*272] = h * pC[t*16 + n];
        }
        __syncthreads();
        {
            const int t0 = c*CT;
            const float* pxc = s_xc[buf];
            #pragma unroll
            for (int r = 0; r < 2; ++r){
                int e = tid + r*256;
                int t = e >> 4, dd = e & 15;
                const float* q = s_p + e*17;
                float s = 0.f;
                #pragma unroll
                for (int k = 0; k < 16; ++k) s += q[k];
                y[(tokbase + t0 + t)*DI + dgb + dd] = s + pxc[e]*s_Dp[dd];
            }
        }
        if (c+1 < NCH) commit(buf^1);
        buf ^= 1;
    }
}

// ---------------------------------------------------------------------------
// K6: out_proj GEMM (512->256) via MFMA, gate y*silu(z) in prologue,
// residual += epilogue. grid (192, 2).
// ---------------------------------------------------------------------------
__global__ __launch_bounds__(256) void k_outproj_mfma(
    const float* __restrict__ y, const float* __restrict__ szb,
    const u16* __restrict__ Wsw, float* __restrict__ residual)
{
    __shared__ u16 sA[16*520];
    const int tid = threadIdx.x;
    {
        const int m = tid >> 4, p = tid & 15, e0 = p*32;
        const int row = blockIdx.x*16 + m;
        const float* yp = y   + (size_t)row*DI + e0;
        const float* sp = szb + (size_t)row*DI + e0;
        unsigned* dp = (unsigned*)sA + (m*520 + e0)/2;
        #pragma unroll
        for (int i = 0; i < 8; ++i){
            float4 yv = *(const float4*)(yp + i*4);
            float4 sv = *(const float4*)(sp + i*4);
            dp[i*2]   = pack2(yv.x*sv.x, yv.y*sv.y);
            dp[i*2+1] = pack2(yv.z*sv.z, yv.w*sv.w);
        }
    }
    __syncthreads();
    const int w = tid >> 6, l = tid & 63;
    f32x4 acc[2] = {{0,0,0,0},{0,0,0,0}};
    const u16* ap0 = sA + (l&15)*520 + (l>>4)*8;
    #pragma unroll
    for (int kc = 0; kc < 16; ++kc){
        short8 a = *(const short8*)(ap0 + kc*32);
        #pragma unroll
        for (int i = 0; i < 2; ++i){
            int ntg = blockIdx.y*8 + w*2 + i;
            short8 b8 = *(const short8*)(Wsw + ((size_t)(ntg*16 + kc)*64 + l)*8);
            acc[i] = __builtin_amdgcn_mfma_f32_16x16x32_bf16(a, b8, acc[i], 0,0,0);
        }
    }
    const int mrow0 = blockIdx.x*16 + (l>>4)*4;
    #pragma unroll
    for (int i = 0; i < 2; ++i){
        int col = (blockIdx.y*8 + w*2 + i)*16 + (l&15);
        #pragma unroll
        for (int r = 0; r < 4; ++r)
            residual[(mrow0+r)*DM + col] += acc[i][r];
    }
}

// ---------------------------------------------------------------------------
// K7: final RMSNorm + heads.
// ---------------------------------------------------------------------------
__global__ __launch_bounds__(256) void k_heads(
    const float* __restrict__ residual, const float* __restrict__ fnorm_w,
    const float* __restrict__ ps_W, const float* __restrict__ ps_b,
    const float* __restrict__ pa_W, const float* __restrict__ pa_b,
    const unsigned* __restrict__ nwraw, void* __restrict__ out)
{
    __shared__ float x1[DM], x2[DM];
    __shared__ float sc[2];
    __shared__ float part[2][4];
    const int tid = threadIdx.x;
    const int bl = blockIdx.x;
    const int b = bl >> 7, l = bl & 127;
    const int fl = get_flag(nwraw);
    const int tok1 = b*SS + 3*l + 1;
    const int tok2 = tok1 + 1;
    float v1 = residual[tok1*DM + tid];
    float v2 = residual[tok2*DM + tid];
    {
        float s1 = v1*v1, s2 = v2*v2;
        #pragma unroll
        for (int off = 32; off >= 1; off >>= 1){
            s1 += __shfl_xor(s1, off, 64);
            s2 += __shfl_xor(s2, off, 64);
        }
        if ((tid & 63) == 0){ part[0][tid>>6] = s1; part[1][tid>>6] = s2; }
    }
    __syncthreads();
    if (tid < 2){
        float s = part[tid][0]+part[tid][1]+part[tid][2]+part[tid][3];
        sc[tid] = rsqrtf(s * (1.f/DM) + 1e-5f);
    }
    __syncthreads();
    float nw = fnorm_w[tid];
    x1[tid] = v1 * sc[0] * nw;
    x2[tid] = v2 * sc[1] * nw;
    __syncthreads();
    const int wv = tid >> 6, ln = tid & 63;
    for (int oi = wv; oi < 9; oi += 4){
        float a = 0.f;
        if (oi < 6){
            #pragma unroll
            for (int k = 0; k < 4; ++k){ int e = ln + 64*k; a += x2[e] * ps_W[e*6 + oi]; }
        } else {
            int j = oi - 6;
            #pragma unroll
            for (int k = 0; k < 4; ++k){ int e = ln + 64*k; a += x1[e] * pa_W[e*3 + j]; }
        }
        #pragma unroll
        for (int off = 32; off >= 1; off >>= 1) a += __shfl_xor(a, off, 64);
        if (ln == 0){
            float r; int idx;
            if (oi < 6){
                r = a + ps_b[oi];
                idx = (b*LL + l)*6 + oi;
            } else {
                int j = oi - 6;
                r = tanhf(a + pa_b[j]);
                idx = BB*LL*6 + (b*LL + l)*3 + j;
            }
            if (fl) ((u16*)out)[idx] = f2bf(r);
            else    ((float*)out)[idx] = r;
        }
    }
}

// ---------------------------------------------------------------------------
extern "C" void kernel_launch(void* const* d_in, const int* in_sizes, int n_in,
                              void* d_out, int out_size, void* d_ws, size_t ws_size,
                              hipStream_t stream)
{
    const int* tsteps = (const int*)d_in[3];
    const unsigned* nwraw = (const unsigned*)d_in[13];

    float* fin = (float*)d_ws;

    const int cidx[23] = {0,1,2,4,5,6,7,8,9,10,12,13,15,16,18,19,20,21,23,24,25,26,27};
    PrepArgs prep;
    const float* fp[28];
    for (int i = 0; i < 28; ++i) fp[i] = nullptr;
    int cur = 0;
    for (int i = 0; i < 23; ++i){
        int gi = cidx[i];
        prep.csrc[i] = d_in[gi];
        prep.cn[i]   = in_sizes[gi];
        prep.coff[i] = cur;
        fp[gi] = fin + cur;
        cur += in_sizes[gi];
        cur = (cur + 3) & ~3;
    }
    float* act = fin + cur;

    float* residual = act;            act += BT*DM;
    float* xc_raw   = act;            act += BT*DI;
    float* sz       = act;            act += BT*DI;
    float* xc       = act;            act += BT*DI;
    float* dtbuf    = act;            act += BT*DI;
    float* ybuf     = act;            act += BT*DI;
    float* dtBC     = act;            act += BT*48;

    u16* wsb    = (u16*)act;
    u16* bb_sw  = wsb;
    u16* in_sw  = bb_sw + 65536;
    u16* out_sw = in_sw + 4*262144;
    u16* xp_sw  = out_sw + 4*131072;

    const int soff[13] = {0, 0, 262144, 524288, 786432,
                          0, 131072, 262144, 393216,
                          0, 24576, 49152, 73728};
    prep.sd[0] = { d_in[11], bb_sw, 256, 256, (256/16)*(256/32)*64 };
    for (int i = 0; i < 4; ++i)
        prep.sd[1+i] = { d_in[14], in_sw + i*262144, 256, 1024,
                         (1024/16)*(256/32)*64 };
    for (int i = 0; i < 4; ++i)
        prep.sd[5+i] = { d_in[22], out_sw + i*131072, 512, 256,
                         (256/16)*(512/32)*64 };
    for (int i = 0; i < 4; ++i)
        prep.sd[9+i] = { d_in[17], xp_sw + i*24576, 512, 48,
                         (48/16)*(512/32)*64 };
    for (int i = 0; i < 13; ++i)
        prep.sd[i].src = (const void*)((const char*)prep.sd[i].src + (size_t)soff[i]*2);

    k_prep<<<SWZ_NB + CNV_NB, 256, 0, stream>>>(prep, nwraw, fin);

    k_embed_mfma<<<dim3(96,2), 256, 0, stream>>>(fp[0], fp[1], fp[2], tsteps,
        fp[4], fp[5], fp[6], fp[7], fp[8], fp[9], fp[10], bb_sw, fp[12], residual);

    for (int lyr = 0; lyr < NL; ++lyr){
        k_rms_inproj_mfma<<<dim3(96,8), 256, 0, stream>>>(residual, fp[13] + lyr*DM,
            in_sw + lyr*262144, xc_raw, sz);
        k_conv_mfma<<<BT/16, 256, 0, stream>>>(xc_raw, fp[15] + lyr*DI*4,
            fp[16] + lyr*DI, xp_sw + lyr*24576, fp[18] + lyr*RK*DI, fp[19] + lyr*DI,
            xc, dtBC, dtbuf);
        k_scan<<<256, 256, 0, stream>>>(dtbuf, dtBC, xc,
            fp[20] + lyr*DI*DSTATE, fp[21] + lyr*DI, ybuf);
        k_outproj_mfma<<<dim3(192,2), 256, 0, stream>>>(ybuf, sz,
            out_sw + lyr*131072, residual);
    }
    k_heads<<<BB*LL, 256, 0, stream>>>(residual, fp[23], fp[24], fp[25], fp[26], fp[27],
                                       nwraw, (u16*)d_out);
}